// Round 2
// baseline (220.497 us; speedup 1.0000x reference)
//
#include <hip/hip_runtime.h>
#include <stdint.h>

// Problem constants (from reference)
#define N_ROWS   32768      // BSZ*TSZ
#define M_CODES  1024
#define D_DIM    256
#define BN       64         // rows per block
#define NBLOCKS  (N_ROWS / BN)   // 512
#define EPS      1.0f       // argmin refinement window (~50 sigma of bf16 dist error)
#define CAND_MAX 16

// Output layout (flat f32, concat in reference return order)
#define OFF_Q      0
#define OFF_CODEP  8388608
#define OFF_PROBP  8388609
#define OFF_INDS   8388610
#define OFF_COMMIT 8421378

typedef __attribute__((ext_vector_type(8))) short bf16x8;
typedef __attribute__((ext_vector_type(8))) unsigned short u16x8;
typedef __attribute__((ext_vector_type(4))) float f32x4;

__device__ __forceinline__ unsigned short f2bf(float f) {
    unsigned int u = __float_as_uint(f);
    u += 0x7FFFu + ((u >> 16) & 1u);   // RNE (inputs finite)
    return (unsigned short)(u >> 16);
}

// ---------------------------------------------------------------------------
// Prep: emb f32 -> bf16 in MFMA-fragment order + ||e||^2 + zero accumulators.
// efrag[c16][ks][lane][8]: holds emb[c16*16 + (lane&15)][ks*32 + (lane>>4)*8 .. +8]
// grid 1024 blocks (one code) x 64 threads
__global__ __launch_bounds__(64) void vq_prep(
    const float* __restrict__ emb,
    unsigned short* __restrict__ efrag, float* __restrict__ enorm,
    float* __restrict__ pprobs_g, unsigned int* __restrict__ counts_g,
    float* __restrict__ commit_g)
{
    const int r = blockIdx.x, t = threadIdx.x;

    // fragment-order pack: threads 0..31 each handle 8 consecutive elems
    if (t < 32) {
        const float4 a = *(const float4*)(emb + r * D_DIM + t * 8);
        const float4 b = *(const float4*)(emb + r * D_DIM + t * 8 + 4);
        u16x8 H;
        H[0] = f2bf(a.x); H[1] = f2bf(a.y); H[2] = f2bf(a.z); H[3] = f2bf(a.w);
        H[4] = f2bf(b.x); H[5] = f2bf(b.y); H[6] = f2bf(b.z); H[7] = f2bf(b.w);
        // ks = t>>2, k-group = t&3, lane = (k-group<<4) | (r&15)
        const int off = (((r >> 4) * 8 + (t >> 2)) * 64 + (((t & 3) << 4) | (r & 15))) * 8;
        *(u16x8*)(efrag + off) = H;
    }

    // ||e||^2 (exact f32) by all 64 threads
    const float4 v = *(const float4*)(emb + r * D_DIM + t * 4);
    float n = v.x * v.x + v.y * v.y + v.z * v.z + v.w * v.w;
    #pragma unroll
    for (int off = 32; off; off >>= 1) n += __shfl_xor(n, off);
    if (t == 0) {
        enorm[r] = n;
        pprobs_g[r] = 0.0f;
        counts_g[r] = 0u;
        if (r == 0) commit_g[0] = 0.0f;
    }
}

// ---------------------------------------------------------------------------
// Main: block = 64 rows x all 1024 codes. 16 waves; wave w = 64 rows x cols [w*64, w*64+64).
// GEMM: single-pass bf16 MFMA (t = ||e||^2 - 2 x.e up to bf16 error);
// epilogue fully register-resident; exact-f32 refinement for argmin near-ties.
__global__ __launch_bounds__(1024, 4) void vq_main(
    const float* __restrict__ xg, const float* __restrict__ embf,
    const unsigned short* __restrict__ efrag, const float* __restrict__ enorm,
    float* __restrict__ pprobs_g, unsigned int* __restrict__ counts_g,
    float* __restrict__ commit_g,
    float* __restrict__ out_q, float* __restrict__ out_inds)
{
    __shared__ char  xs[32768];          // x tile: 64 rows x 256 bf16, XOR-swizzled
    __shared__ float wmin[16][64];       // per-wave per-row partial min
    __shared__ float wsum[16][64];       // per-wave per-row partial expsum
    __shared__ float rmin[64];
    __shared__ float rinv[64];
    __shared__ int   cand[64][CAND_MAX];
    __shared__ int   ccnt[64];
    __shared__ int   kidx[64];

    const int tid  = threadIdx.x;
    const int wave = tid >> 6, lane = tid & 63;
    const int lrow = lane & 15, lg = lane >> 4;
    const int sw   = (lrow & 7) << 4;
    const int row0 = blockIdx.x * BN;
    const int wc0  = wave * 64;          // wave's first col

    // ---- stage x tile (thread: row = tid>>4, 16 elems at (tid&15)*16)
    {
        const int row = tid >> 4, kc = tid & 15;
        const float* xr = xg + (size_t)(row0 + row) * D_DIM + kc * 16;
        const float4 v0 = *(const float4*)(xr);
        const float4 v1 = *(const float4*)(xr + 4);
        const float4 v2 = *(const float4*)(xr + 8);
        const float4 v3 = *(const float4*)(xr + 12);
        u16x8 H0, H1;
        H0[0] = f2bf(v0.x); H0[1] = f2bf(v0.y); H0[2] = f2bf(v0.z); H0[3] = f2bf(v0.w);
        H0[4] = f2bf(v1.x); H0[5] = f2bf(v1.y); H0[6] = f2bf(v1.z); H0[7] = f2bf(v1.w);
        H1[0] = f2bf(v2.x); H1[1] = f2bf(v2.y); H1[2] = f2bf(v2.z); H1[3] = f2bf(v2.w);
        H1[4] = f2bf(v3.x); H1[5] = f2bf(v3.y); H1[6] = f2bf(v3.z); H1[7] = f2bf(v3.w);
        const int rsw = (row & 7) << 4;
        *(u16x8*)(xs + ((row * 512 + kc * 32) ^ rsw))      = H0;
        *(u16x8*)(xs + ((row * 512 + kc * 32 + 16) ^ rsw)) = H1;
        if (tid < 64) ccnt[tid] = 0;
    }
    __syncthreads();

    // ---- GEMM: acc[rf][cf][j] = dot(x[rf*16 + lg*4 + j ... wait row map], e[col])
    // C/D map: row_local = lg*4 + j, col_local = lrow (m89-verified)
    f32x4 acc[4][4];
    #pragma unroll
    for (int rf = 0; rf < 4; ++rf)
        #pragma unroll
        for (int cf = 0; cf < 4; ++cf)
            acc[rf][cf] = (f32x4){0.f, 0.f, 0.f, 0.f};

    const char* bbase = (const char*)efrag + lane * 16 + wave * 32768;  // (wave*4+cf)*8*1024 + ks*1024 + lane*16
    #pragma unroll
    for (int ks = 0; ks < 8; ++ks) {
        bf16x8 a[4];
        #pragma unroll
        for (int rf = 0; rf < 4; ++rf)
            a[rf] = *(const bf16x8*)(xs + (((rf * 16 + lrow) * 512 + ks * 64 + lg * 16) ^ sw));
        #pragma unroll
        for (int cf = 0; cf < 4; ++cf) {
            const bf16x8 b = *(const bf16x8*)(bbase + cf * 8192 + ks * 1024);
            acc[0][cf] = __builtin_amdgcn_mfma_f32_16x16x32_bf16(a[0], b, acc[0][cf], 0, 0, 0);
            acc[1][cf] = __builtin_amdgcn_mfma_f32_16x16x32_bf16(a[1], b, acc[1][cf], 0, 0, 0);
            acc[2][cf] = __builtin_amdgcn_mfma_f32_16x16x32_bf16(a[2], b, acc[2][cf], 0, 0, 0);
            acc[3][cf] = __builtin_amdgcn_mfma_f32_16x16x32_bf16(a[3], b, acc[3][cf], 0, 0, 0);
        }
    }

    // convert acc -> t = ||e||^2 - 2*dot  (registers only)
    #pragma unroll
    for (int cf = 0; cf < 4; ++cf) {
        const float en = enorm[wc0 + cf * 16 + lrow];
        #pragma unroll
        for (int rf = 0; rf < 4; ++rf)
            #pragma unroll
            for (int j = 0; j < 4; ++j)
                acc[rf][cf][j] = en - 2.0f * acc[rf][cf][j];
    }

    // ---- E1: per-wave per-row min over this wave's 64 cols
    #pragma unroll
    for (int rf = 0; rf < 4; ++rf) {
        #pragma unroll
        for (int j = 0; j < 4; ++j) {
            const int row = rf * 16 + lg * 4 + j;
            float m = fminf(fminf(acc[rf][0][j], acc[rf][1][j]),
                            fminf(acc[rf][2][j], acc[rf][3][j]));
            m = fminf(m, __shfl_xor(m, 1));
            m = fminf(m, __shfl_xor(m, 2));
            m = fminf(m, __shfl_xor(m, 4));
            m = fminf(m, __shfl_xor(m, 8));
            if (lrow == 0) wmin[wave][row] = m;
        }
    }
    __syncthreads();

    // ---- R1: cross-wave min -> rmin[row]. wave w owns rows w*4..w*4+3.
    {
        const int row = wave * 4 + lg;
        float m = wmin[lrow][row];
        m = fminf(m, __shfl_xor(m, 1));
        m = fminf(m, __shfl_xor(m, 2));
        m = fminf(m, __shfl_xor(m, 4));
        m = fminf(m, __shfl_xor(m, 8));
        if (lrow == 0) rmin[row] = m;
    }
    __syncthreads();

    // ---- E2+E3: candidate scan + per-wave expsum partials
    #pragma unroll
    for (int rf = 0; rf < 4; ++rf) {
        #pragma unroll
        for (int j = 0; j < 4; ++j) {
            const int row = rf * 16 + lg * 4 + j;
            const float m = rmin[row];
            float s = 0.f;
            #pragma unroll
            for (int cf = 0; cf < 4; ++cf) {
                const float d = acc[rf][cf][j];
                if (d <= m + EPS) {
                    const int pos = atomicAdd(&ccnt[row], 1);
                    if (pos < CAND_MAX) cand[row][pos] = wc0 + cf * 16 + lrow;
                }
                s += __expf(m - d);
            }
            s += __shfl_xor(s, 1); s += __shfl_xor(s, 2);
            s += __shfl_xor(s, 4); s += __shfl_xor(s, 8);
            if (lrow == 0) wsum[wave][row] = s;
        }
    }
    __syncthreads();

    // ---- R2: expsum combine -> rinv; exact-f32 argmin refinement -> kidx/inds/counts
    {
        const int row = wave * 4 + lg;
        float s = wsum[lrow][row];
        s += __shfl_xor(s, 1); s += __shfl_xor(s, 2);
        s += __shfl_xor(s, 4); s += __shfl_xor(s, 8);
        if (lrow == 0) rinv[row] = 1.0f / s;

        for (int q = 0; q < 4; ++q) {
            const int r  = wave * 4 + q;
            const int rg = row0 + r;
            const int n  = min(ccnt[r], CAND_MAX);
            const float4 x4 = *(const float4*)(xg + (size_t)rg * D_DIM + lane * 4);
            float best = 3.4e38f; int bcol = 0x7fffffff;
            for (int i = 0; i < n; ++i) {
                const int c = cand[r][i];
                const float4 e4 = *(const float4*)(embf + (size_t)c * D_DIM + lane * 4);
                float dt = x4.x * e4.x + x4.y * e4.y + x4.z * e4.z + x4.w * e4.w;
                dt += __shfl_xor(dt, 1);  dt += __shfl_xor(dt, 2);
                dt += __shfl_xor(dt, 4);  dt += __shfl_xor(dt, 8);
                dt += __shfl_xor(dt, 16); dt += __shfl_xor(dt, 32);
                const float t = enorm[c] - 2.0f * dt;   // ||x||^2 cancels within row
                if (t < best || (t == best && c < bcol)) { best = t; bcol = c; }
            }
            if (lane == 0) {
                kidx[r] = bcol;
                out_inds[rg] = (float)bcol;
                atomicAdd(&counts_g[bcol], 1u);
            }
        }
    }
    __syncthreads();

    // ---- E4: avg-softmax per-col accumulation (second exp pass, register-fed)
    #pragma unroll
    for (int cf = 0; cf < 4; ++cf) {
        float t = 0.f;
        #pragma unroll
        for (int rf = 0; rf < 4; ++rf)
            #pragma unroll
            for (int j = 0; j < 4; ++j) {
                const int row = rf * 16 + lg * 4 + j;
                t += __expf(rmin[row] - acc[rf][cf][j]) * rinv[row];
            }
        t += __shfl_xor(t, 16);
        t += __shfl_xor(t, 32);
        if (lg == 0) unsafeAtomicAdd(&pprobs_g[wc0 + cf * 16 + lrow], t);
    }

    // ---- E5: gather quantized rows + commitment
    {
        float cacc = 0.f;
        for (int q = 0; q < 4; ++q) {
            const int r  = wave * 4 + q;
            const int rg = row0 + r;
            const int ki = kidx[r];
            const float4 e4 = *(const float4*)(embf + (size_t)ki * D_DIM + lane * 4);
            const float4 x4 = *(const float4*)(xg + (size_t)rg * D_DIM + lane * 4);
            *(float4*)(out_q + (size_t)rg * D_DIM + lane * 4) = e4;
            const float dx = x4.x - e4.x, dy = x4.y - e4.y;
            const float dz = x4.z - e4.z, dw = x4.w - e4.w;
            cacc += dx * dx + dy * dy + dz * dz + dw * dw;
        }
        cacc += __shfl_xor(cacc, 1);  cacc += __shfl_xor(cacc, 2);
        cacc += __shfl_xor(cacc, 4);  cacc += __shfl_xor(cacc, 8);
        cacc += __shfl_xor(cacc, 16); cacc += __shfl_xor(cacc, 32);
        if (lane == 0) unsafeAtomicAdd(commit_g, cacc);
    }
}

// ---------------------------------------------------------------------------
// Final: the three scalars. 1 block x 1024 threads.
__global__ __launch_bounds__(1024) void vq_final(
    const float* __restrict__ pprobs_g, const unsigned int* __restrict__ counts_g,
    const float* __restrict__ commit_g, float* __restrict__ out)
{
    __shared__ float red1[16], red2[16];
    const int tid = threadIdx.x, wave = tid >> 6, lane = tid & 63;

    const float p_hard = (float)counts_g[tid] * (1.0f / (float)N_ROWS);
    float t1 = p_hard * log2f(p_hard + 1e-10f);
    const float p_avg = pprobs_g[tid] * (1.0f / (float)N_ROWS);
    float t2 = p_avg * log2f(p_avg + 1e-10f);

    #pragma unroll
    for (int off = 32; off; off >>= 1) { t1 += __shfl_xor(t1, off); t2 += __shfl_xor(t2, off); }
    if (lane == 0) { red1[wave] = t1; red2[wave] = t2; }
    __syncthreads();
    if (tid == 0) {
        float s1 = 0.0f, s2 = 0.0f;
        #pragma unroll
        for (int i = 0; i < 16; ++i) { s1 += red1[i]; s2 += red2[i]; }
        out[OFF_CODEP]  = -s1;
        out[OFF_PROBP]  = -s2;
        out[OFF_COMMIT] = commit_g[0] * (1.0f / (float)(N_ROWS * D_DIM));
    }
}

// ---------------------------------------------------------------------------
extern "C" void kernel_launch(void* const* d_in, const int* in_sizes, int n_in,
                              void* d_out, int out_size, void* d_ws, size_t ws_size,
                              hipStream_t stream)
{
    (void)in_sizes; (void)n_in; (void)out_size; (void)ws_size;
    const float* xg   = (const float*)d_in[0];
    const float* embf = (const float*)d_in[1];
    float* out = (float*)d_out;

    // ws layout (~525 KB): efrag | enorm | pprobs_g | counts_g | commit_g
    char* ws = (char*)d_ws;
    unsigned short* efrag    = (unsigned short*)(ws);
    float*          enorm    = (float*)(ws + 524288);
    float*          pprobs_g = (float*)(ws + 528384);
    unsigned int*   counts_g = (unsigned int*)(ws + 532480);
    float*          commit_g = (float*)(ws + 536576);

    hipLaunchKernelGGL(vq_prep, dim3(M_CODES), dim3(64), 0, stream,
                       embf, efrag, enorm, pprobs_g, counts_g, commit_g);

    hipLaunchKernelGGL(vq_main, dim3(NBLOCKS), dim3(1024), 0, stream,
                       xg, embf, efrag, enorm, pprobs_g, counts_g, commit_g,
                       out + OFF_Q, out + OFF_INDS);

    hipLaunchKernelGGL(vq_final, dim3(1), dim3(1024), 0, stream,
                       pprobs_g, counts_g, commit_g, out);
}